// Round 1
// baseline (138.466 us; speedup 1.0000x reference)
//
#include <hip/hip_runtime.h>

// CompositeBezierCurve: eval degree-7 Bezier spline at 4M points.
// inputs: d_in[0]=x_eval[N] f32, d_in[1]=knots_x[nseg+1] f32,
//         d_in[2]=control_points[nseg][8][3] f32
// output: d_out[N][3] f32

#define PTS_PER_THREAD 4

__global__ __launch_bounds__(256) void bezier_eval_kernel(
    const float* __restrict__ x_eval,
    const float* __restrict__ knots,   // nseg+1 entries
    const float* __restrict__ cp,      // [nseg][8][3]
    float* __restrict__ out,           // [n][3]
    int n, int nseg)
{
    const int tid  = blockIdx.x * blockDim.x + threadIdx.x;
    const int base = tid * PTS_PER_THREAD;
    if (base >= n) return;

    // wave-uniform: last knot + inverse average spacing (guess only; fixup below)
    const float xend   = knots[nseg];
    const float inv_dx = (float)nseg / xend;

    float xs[PTS_PER_THREAD];
    if (base + PTS_PER_THREAD <= n) {
        float4 xv = *(const float4*)(x_eval + base);
        xs[0] = xv.x; xs[1] = xv.y; xs[2] = xv.z; xs[3] = xv.w;
    } else {
        for (int p = 0; p < PTS_PER_THREAD; ++p)
            xs[p] = (base + p < n) ? x_eval[base + p] : 0.0f;
    }

    float res[PTS_PER_THREAD * 3];

#pragma unroll
    for (int p = 0; p < PTS_PER_THREAD; ++p) {
        float x  = xs[p];
        float xt = fmodf(x, xend);          // jnp.mod == lax.rem for x>=0
        if (xt < 0.0f) xt += xend;          // safety (inputs are >=0)

        int idx = (int)floorf(xt * inv_dx);
        idx = min(max(idx, 0), nseg - 1);

        float k0 = knots[idx];
        float k1 = knots[idx + 1];
        // fix-up so idx matches searchsorted(xstart, xt, 'right')-1 exactly
        while (idx > 0 && xt < k0)          { --idx; k1 = k0; k0 = knots[idx]; }
        while (idx < nseg - 1 && xt >= k1)  { ++idx; k0 = k1; k1 = knots[idx + 1]; }

        const float s = (xt - k0) / (k1 - k0);
        const float t = 1.0f - s;

        // powers (match reference's s^k * (1-s)^(7-k) in fp32)
        const float s2 = s * s,  s3 = s2 * s, s4 = s2 * s2, s5 = s4 * s, s6 = s3 * s3, s7 = s6 * s;
        const float t2 = t * t,  t3 = t2 * t, t4 = t2 * t2, t5 = t4 * t, t6 = t3 * t3, t7 = t6 * t;

        float M0 = t7;
        float M1 = 7.0f  * s  * t6;
        float M2 = 21.0f * s2 * t5;
        float M3 = 35.0f * s3 * t4;
        float M4 = 35.0f * s4 * t3;
        float M5 = 21.0f * s5 * t2;
        float M6 = 7.0f  * s6 * t;
        float M7 = s7;

        // 96B row, 16B-aligned (24 floats): six float4 loads
        const float4* c = (const float4*)(cp + (size_t)idx * 24);
        float4 c0 = c[0], c1 = c[1], c2 = c[2], c3 = c[3], c4 = c[4], c5 = c[5];

        // layout [k][d], elem (k,d) at 3k+d
        float o0 = M0*c0.x + M1*c0.w + M2*c1.z + M3*c2.y + M4*c3.x + M5*c3.w + M6*c4.z + M7*c5.y;
        float o1 = M0*c0.y + M1*c1.x + M2*c1.w + M3*c2.z + M4*c3.y + M5*c4.x + M6*c4.w + M7*c5.z;
        float o2 = M0*c0.z + M1*c1.y + M2*c2.x + M3*c2.w + M4*c3.z + M5*c4.y + M6*c5.x + M7*c5.w;

        res[p*3 + 0] = o0;
        res[p*3 + 1] = o1;
        res[p*3 + 2] = o2;
    }

    if (base + PTS_PER_THREAD <= n) {
        float4* ov = (float4*)(out + (size_t)base * 3);
        ov[0] = make_float4(res[0], res[1], res[2],  res[3]);
        ov[1] = make_float4(res[4], res[5], res[6],  res[7]);
        ov[2] = make_float4(res[8], res[9], res[10], res[11]);
    } else {
        for (int p = 0; p < PTS_PER_THREAD; ++p)
            if (base + p < n)
                for (int d = 0; d < 3; ++d)
                    out[(size_t)(base + p) * 3 + d] = res[p*3 + d];
    }
}

extern "C" void kernel_launch(void* const* d_in, const int* in_sizes, int n_in,
                              void* d_out, int out_size, void* d_ws, size_t ws_size,
                              hipStream_t stream) {
    const float* x_eval = (const float*)d_in[0];
    const float* knots  = (const float*)d_in[1];
    const float* cp     = (const float*)d_in[2];
    float* out          = (float*)d_out;

    const int n    = in_sizes[0];
    const int nseg = in_sizes[1] - 1;

    const int threads = 256;
    const int pts_per_block = threads * PTS_PER_THREAD;
    const int blocks = (n + pts_per_block - 1) / pts_per_block;

    bezier_eval_kernel<<<blocks, threads, 0, stream>>>(x_eval, knots, cp, out, n, nseg);
}

// Round 2
// 114.424 us; speedup vs baseline: 1.2101x; 1.2101x over previous
//
#include <hip/hip_runtime.h>
#include <hip/hip_fp16.h>

// CompositeBezierCurve: eval degree-7 Bezier spline at 4M points.
// R2 design: pre-pass packs each segment into ONE 64B cache line in d_ws:
//   [xstart f32][xnext f32][pad 8B][24 x fp16 cp, planar: h[d*8+k] = cp[k][d]]
// Main kernel: 4 lanes cooperate per point; each loads one 16B quarter of the
// row -> coalescer merges the group's 64B into a single L1 line lookup.
// Lane q=0 holds the header (xstart,xnext broadcast via shfl); lanes q=1..3
// each compute one output dimension (planar layout => identical M weights
// across lanes, no divergence).

__global__ __launch_bounds__(256) void pack_rows_kernel(
    const float* __restrict__ knots,
    const float* __restrict__ cp,      // [nseg][8][3] f32
    float4* __restrict__ rows,         // [nseg][4] float4 (64B rows)
    int nseg)
{
    int i = blockIdx.x * blockDim.x + threadIdx.x;
    if (i >= nseg) return;

    union { float f[16]; float4 v[4]; unsigned u[16]; } row;
    row.f[0] = knots[i];
    row.f[1] = knots[i + 1];
    row.f[2] = 0.0f;
    row.f[3] = 0.0f;

    const float* c = cp + (size_t)i * 24;   // elem (k,d) at 3k+d
#pragma unroll
    for (int d = 0; d < 3; ++d) {
#pragma unroll
        for (int k = 0; k < 8; k += 2) {
            __half2 hh = __halves2half2(__float2half(c[3*k + d]),
                                        __float2half(c[3*(k+1) + d]));
            union { __half2 h; unsigned u; } cvt; cvt.h = hh;
            row.u[4 + ((d*8 + k) >> 1)] = cvt.u;
        }
    }

    float4* dst = rows + (size_t)i * 4;
    dst[0] = row.v[0];
    dst[1] = row.v[1];
    dst[2] = row.v[2];
    dst[3] = row.v[3];
}

#define ITERS 4

__global__ __launch_bounds__(256) void bezier_eval_packed(
    const float* __restrict__ x_eval,
    const float* __restrict__ knots,
    const float4* __restrict__ rows,   // [nseg][4]
    float* __restrict__ out,           // [n][3]
    int n, int nseg)
{
    const int l  = threadIdx.x & 63;   // lane in wave
    const int wv = threadIdx.x >> 6;   // wave in block
    const int g  = l >> 2;             // group 0..15 (one point each)
    const int q  = l & 3;              // quarter within row
    const int gb = l & ~3;             // group's base lane

    const float xend   = knots[nseg];
    const float inv_dx = (float)nseg / xend;

    const int bbase = blockIdx.x * (256 * ITERS) / 4 + wv * (16 * ITERS);
    // per block: 4 waves x 16 points x ITERS = 64*ITERS points

#pragma unroll
    for (int j = 0; j < ITERS; ++j) {
        const int p = bbase + j * 16 + g;
        if (p >= n) continue;

        float x  = x_eval[p];                       // 4 lanes same addr: merged
        float xt = (x >= xend) ? (x - xend) : x;    // == fmod for x < 2*xend
        if (xt < 0.0f) xt = 0.0f;

        int idx = (int)(xt * inv_dx);
        idx = min(max(idx, 0), nseg - 1);

        float4 f = rows[idx * 4 + q];
        float xs = __shfl(f.x, gb, 64);
        float xn = __shfl(f.y, gb, 64);
        // fixup so idx matches searchsorted(xstart, xt, 'right')-1 exactly
        while (xt < xs && idx > 0) {
            --idx; f = rows[idx * 4 + q];
            xs = __shfl(f.x, gb, 64); xn = __shfl(f.y, gb, 64);
        }
        while (xt >= xn && idx < nseg - 1) {
            ++idx; f = rows[idx * 4 + q];
            xs = __shfl(f.x, gb, 64); xn = __shfl(f.y, gb, 64);
        }

        const float s = (xt - xs) / (xn - xs);
        const float t = 1.0f - s;
        const float s2 = s*s, s3 = s2*s, s4 = s2*s2, s5 = s4*s, s6 = s3*s3, s7 = s6*s;
        const float t2 = t*t, t3 = t2*t, t4 = t2*t2, t5 = t4*t, t6 = t3*t3, t7 = t6*t;
        const float M[8] = { t7,
                             7.0f  * s  * t6,
                             21.0f * s2 * t5,
                             35.0f * s3 * t4,
                             35.0f * s4 * t3,
                             21.0f * s5 * t2,
                             7.0f  * s6 * t,
                             s7 };

        if (q != 0) {
            // f = 8 halves of cp[k][q-1], k ascending
            union { float4 v; unsigned u[4]; } uu; uu.v = f;
            float acc = 0.0f;
#pragma unroll
            for (int w = 0; w < 4; ++w) {
                union { unsigned u; __half2 h; } cvt; cvt.u = uu.u[w];
                acc = fmaf(M[2*w],     __low2float(cvt.h),  acc);
                acc = fmaf(M[2*w + 1], __high2float(cvt.h), acc);
            }
            out[p * 3 + (q - 1)] = acc;   // 48 contiguous dwords per wave
        }
    }
}

// ---- fallback (R1 kernel) if ws_size is too small for the packed rows ----
#define PTS_PER_THREAD 4
__global__ __launch_bounds__(256) void bezier_eval_direct(
    const float* __restrict__ x_eval,
    const float* __restrict__ knots,
    const float* __restrict__ cp,
    float* __restrict__ out,
    int n, int nseg)
{
    const int tid  = blockIdx.x * blockDim.x + threadIdx.x;
    const int base = tid * PTS_PER_THREAD;
    if (base >= n) return;
    const float xend   = knots[nseg];
    const float inv_dx = (float)nseg / xend;
    float xs4[PTS_PER_THREAD];
    if (base + PTS_PER_THREAD <= n) {
        float4 xv = *(const float4*)(x_eval + base);
        xs4[0] = xv.x; xs4[1] = xv.y; xs4[2] = xv.z; xs4[3] = xv.w;
    } else {
        for (int p = 0; p < PTS_PER_THREAD; ++p)
            xs4[p] = (base + p < n) ? x_eval[base + p] : 0.0f;
    }
    float res[PTS_PER_THREAD * 3];
#pragma unroll
    for (int p = 0; p < PTS_PER_THREAD; ++p) {
        float x  = xs4[p];
        float xt = fmodf(x, xend);
        if (xt < 0.0f) xt += xend;
        int idx = (int)floorf(xt * inv_dx);
        idx = min(max(idx, 0), nseg - 1);
        float k0 = knots[idx], k1 = knots[idx + 1];
        while (idx > 0 && xt < k0)         { --idx; k1 = k0; k0 = knots[idx]; }
        while (idx < nseg - 1 && xt >= k1) { ++idx; k0 = k1; k1 = knots[idx + 1]; }
        const float s = (xt - k0) / (k1 - k0);
        const float t = 1.0f - s;
        const float s2=s*s, s3=s2*s, s4=s2*s2, s5=s4*s, s6=s3*s3, s7=s6*s;
        const float t2=t*t, t3=t2*t, t4=t2*t2, t5=t4*t, t6=t3*t3, t7=t6*t;
        float M0=t7, M1=7.f*s*t6, M2=21.f*s2*t5, M3=35.f*s3*t4,
              M4=35.f*s4*t3, M5=21.f*s5*t2, M6=7.f*s6*t, M7=s7;
        const float4* c = (const float4*)(cp + (size_t)idx * 24);
        float4 c0=c[0], c1=c[1], c2=c[2], c3=c[3], c4=c[4], c5=c[5];
        res[p*3+0] = M0*c0.x + M1*c0.w + M2*c1.z + M3*c2.y + M4*c3.x + M5*c3.w + M6*c4.z + M7*c5.y;
        res[p*3+1] = M0*c0.y + M1*c1.x + M2*c1.w + M3*c2.z + M4*c3.y + M5*c4.x + M6*c4.w + M7*c5.z;
        res[p*3+2] = M0*c0.z + M1*c1.y + M2*c2.x + M3*c2.w + M4*c3.z + M5*c4.y + M6*c5.x + M7*c5.w;
    }
    if (base + PTS_PER_THREAD <= n) {
        float4* ov = (float4*)(out + (size_t)base * 3);
        ov[0] = make_float4(res[0], res[1], res[2],  res[3]);
        ov[1] = make_float4(res[4], res[5], res[6],  res[7]);
        ov[2] = make_float4(res[8], res[9], res[10], res[11]);
    } else {
        for (int p = 0; p < PTS_PER_THREAD; ++p)
            if (base + p < n)
                for (int d = 0; d < 3; ++d)
                    out[(size_t)(base + p) * 3 + d] = res[p*3 + d];
    }
}

extern "C" void kernel_launch(void* const* d_in, const int* in_sizes, int n_in,
                              void* d_out, int out_size, void* d_ws, size_t ws_size,
                              hipStream_t stream) {
    const float* x_eval = (const float*)d_in[0];
    const float* knots  = (const float*)d_in[1];
    const float* cp     = (const float*)d_in[2];
    float* out          = (float*)d_out;

    const int n    = in_sizes[0];
    const int nseg = in_sizes[1] - 1;

    const size_t rows_bytes = (size_t)nseg * 64;
    if (ws_size >= rows_bytes) {
        float4* rows = (float4*)d_ws;
        pack_rows_kernel<<<(nseg + 255) / 256, 256, 0, stream>>>(knots, cp, rows, nseg);
        const int pts_per_block = 64 * ITERS;   // 4 waves x 16 points x ITERS
        const int blocks = (n + pts_per_block - 1) / pts_per_block;
        bezier_eval_packed<<<blocks, 256, 0, stream>>>(x_eval, knots, rows, out, n, nseg);
    } else {
        const int threads = 256;
        const int pts_per_block = threads * PTS_PER_THREAD;
        const int blocks = (n + pts_per_block - 1) / pts_per_block;
        bezier_eval_direct<<<blocks, threads, 0, stream>>>(x_eval, knots, cp, out, n, nseg);
    }
}